// Round 4
// baseline (176.927 us; speedup 1.0000x reference)
//
#include <hip/hip_runtime.h>
#include <math.h>

#define Bsz 8
#define Cch 512
#define Npx 1024
#define TOPK 12

typedef __attribute__((ext_vector_type(8))) short bf16x8;
typedef __attribute__((ext_vector_type(4))) float f32x4;

__device__ __forceinline__ unsigned short f2bf(float x) {
    unsigned u = __float_as_uint(x);
    u += 0x7FFF + ((u >> 16) & 1);
    return (unsigned short)(u >> 16);
}
__device__ __forceinline__ float bf2f(unsigned short h) {
    return __uint_as_float(((unsigned)h) << 16);
}

// ---------------- reduction helpers (blockDim.x == 256) ----------------
__device__ __forceinline__ float warp_sum64(float v) {
    for (int o = 32; o > 0; o >>= 1) v += __shfl_down(v, o);
    return v;
}
__device__ __forceinline__ float warp_max64(float v) {
    for (int o = 32; o > 0; o >>= 1) v = fmaxf(v, __shfl_down(v, o));
    return v;
}
__device__ __forceinline__ float block_sum256(float v, float* s4) {
    v = warp_sum64(v);
    int lane = threadIdx.x & 63, w = threadIdx.x >> 6;
    __syncthreads();
    if (lane == 0) s4[w] = v;
    __syncthreads();
    return s4[0] + s4[1] + s4[2] + s4[3];
}
__device__ __forceinline__ float block_max256(float v, float* s4) {
    v = warp_max64(v);
    int lane = threadIdx.x & 63, w = threadIdx.x >> 6;
    __syncthreads();
    if (lane == 0) s4[w] = v;
    __syncthreads();
    return fmaxf(fmaxf(s4[0], s4[1]), fmaxf(s4[2], s4[3]));
}

// ---------------- 1: masked average pool ----------------
__global__ void k_pool(const float* __restrict__ sf, const int* __restrict__ mask,
                       float* __restrict__ FPo, float* __restrict__ BPo) {
    __shared__ float s4[4];
    int c = blockIdx.x, b = blockIdx.y, t = threadIdx.x;
    const float* f = sf + ((size_t)b * Cch + c) * Npx;
    const int* m = mask + (size_t)b * Npx;
    float sumf = 0.f, sumb = 0.f, cf = 0.f, cb = 0.f;
    for (int p = t; p < Npx; p += 256) {
        float v = f[p];
        if (m[p] == 1) { sumf += v; cf += 1.f; }
        else           { sumb += v; cb += 1.f; }
    }
    sumf = block_sum256(sumf, s4);
    cf   = block_sum256(cf, s4);
    sumb = block_sum256(sumb, s4);
    cb   = block_sum256(cb, s4);
    if (t == 0) {
        FPo[b * Cch + c] = sumf / (cf + 1e-5f);
        BPo[b * Cch + c] = sumb / (cb + 1e-5f);
    }
}

// ---------------- 2: per-pixel 2-way similarity softmax ----------------
__global__ void k_pred(const float* __restrict__ fq, const float* __restrict__ FP,
                       const float* __restrict__ BP, float* __restrict__ predf,
                       float* __restrict__ predb, float* __restrict__ invn) {
    __shared__ float sFP[Cch], sBP[Cch], s4[4];
    __shared__ float rdf[8][32], rdb[8][32], rqq[8][32];
    int b = blockIdx.y, t = threadIdx.x;
    int tx = t & 31, ty = t >> 5;
    int p = blockIdx.x * 32 + tx;
    for (int c = t; c < Cch; c += 256) { sFP[c] = FP[b * Cch + c]; sBP[c] = BP[b * Cch + c]; }
    __syncthreads();
    float nf = 0.f, nb = 0.f;
    for (int c = t; c < Cch; c += 256) { nf += sFP[c] * sFP[c]; nb += sBP[c] * sBP[c]; }
    nf = sqrtf(block_sum256(nf, s4));
    nb = sqrtf(block_sum256(nb, s4));
    const float* q = fq + (size_t)b * Cch * Npx + p;
    float df = 0.f, db = 0.f, qq = 0.f;
    int c0 = ty * 64;
    #pragma unroll 4
    for (int c = 0; c < 64; c++) {
        float v = q[(size_t)(c0 + c) * Npx];
        df += v * sFP[c0 + c]; db += v * sBP[c0 + c]; qq += v * v;
    }
    rdf[ty][tx] = df; rdb[ty][tx] = db; rqq[ty][tx] = qq;
    __syncthreads();
    for (int s = 4; s > 0; s >>= 1) {
        if (ty < s) {
            rdf[ty][tx] += rdf[ty + s][tx];
            rdb[ty][tx] += rdb[ty + s][tx];
            rqq[ty][tx] += rqq[ty + s][tx];
        }
        __syncthreads();
    }
    if (ty == 0) {
        float nq = sqrtf(rqq[0][tx]);
        float simf = 10.f * rdf[0][tx] / fmaxf(nq * nf, 1e-8f);
        float simb = 10.f * rdb[0][tx] / fmaxf(nq * nb, 1e-8f);
        predf[b * Npx + p] = 1.f / (1.f + expf(simb - simf));
        predb[b * Npx + p] = 1.f / (1.f + expf(simf - simb));
        invn[b * Npx + p] = 1.f / nq;
    }
}

// ---------------- 3: select weights (threshold else top-12) ----------------
__global__ void __launch_bounds__(1024) k_select(const float* __restrict__ pred, float thres,
                                                 float* __restrict__ w, float* __restrict__ cnt) {
    __shared__ float v[Npx];
    __shared__ float rv[Npx];
    __shared__ int   ri[Npx];
    __shared__ int   cnts;
    int b = blockIdx.x, t = threadIdx.x;
    float p = pred[b * Npx + t];
    int m = (p > thres) ? 1 : 0;
    if (t == 0) cnts = 0;
    __syncthreads();
    atomicAdd(&cnts, m);
    __syncthreads();
    if (cnts > 0) {
        w[b * Npx + t] = m ? 1.f : 0.f;
        if (t == 0) cnt[b] = (float)cnts;
    } else {
        v[t] = p;
        __syncthreads();
        float wv = 0.f;
        for (int k = 0; k < TOPK; k++) {
            rv[t] = v[t]; ri[t] = t;
            __syncthreads();
            for (int s = 512; s > 0; s >>= 1) {
                if (t < s) {
                    float a = rv[t], bb = rv[t + s];
                    int ia = ri[t], ib = ri[t + s];
                    if (bb > a || (bb == a && ib < ia)) { rv[t] = bb; ri[t] = ib; }
                }
                __syncthreads();
            }
            int win = ri[0];
            if (t == win) { wv = 1.f; v[t] = -INFINITY; }
            __syncthreads();
        }
        w[b * Npx + t] = wv;
        if (t == 0) cnt[b] = (float)TOPK;
    }
}

// ---------------- 4: both weighted prototypes in one pass ----------------
__global__ void k_proto2(const float* __restrict__ fq, const float* __restrict__ wf,
                         const float* __restrict__ wb, const float* __restrict__ cnt,
                         float* __restrict__ fgp, float* __restrict__ bgp) {
    __shared__ float s4[4];
    int c = blockIdx.x, b = blockIdx.y, t = threadIdx.x;
    const float* f = fq + ((size_t)b * Cch + c) * Npx;
    const float* wwf = wf + (size_t)b * Npx;
    const float* wwb = wb + (size_t)b * Npx;
    float sf_ = 0.f, sb_ = 0.f;
    for (int p = t; p < Npx; p += 256) {
        float v = f[p];
        sf_ += v * wwf[p];
        sb_ += v * wwb[p];
    }
    sf_ = block_sum256(sf_, s4);
    sb_ = block_sum256(sb_, s4);
    if (t == 0) {
        fgp[b * Cch + c] = sf_ / cnt[b];
        bgp[b * Cch + c] = sb_ / cnt[Bsz + b];
    }
}

// ---------------- 4b: bf16 cast + transpose -> Ft[b][i][c] only ----------------
__global__ void k_cast(const float* __restrict__ fq, unsigned short* __restrict__ Ft) {
    __shared__ unsigned short tt[32][33];
    int b = blockIdx.z;
    int i0 = blockIdx.x * 32, c0 = blockIdx.y * 32;
    int tid = threadIdx.x;
    int col = tid & 31, rr = tid >> 5;
    const float* F = fq + (size_t)b * Cch * Npx;
    unsigned short* FtB = Ft + (size_t)b * Npx * Cch;
    for (int r = rr; r < 32; r += 8) {
        tt[r][col] = f2bf(F[(size_t)(c0 + r) * Npx + i0 + col]);
    }
    __syncthreads();
    for (int r = rr; r < 32; r += 8) {
        FtB[(size_t)(i0 + r) * Cch + c0 + col] = tt[col][r];
    }
}

// ---------------- 4c: compact selected columns (order-preserving scan) ------
// grid Bsz, block 1024
__global__ void __launch_bounds__(1024) k_compact(const float* __restrict__ wb,
                                                  const float* __restrict__ invn,
                                                  int* __restrict__ nsel, int* __restrict__ jidx,
                                                  float* __restrict__ ivg) {
    __shared__ int sc[1024];
    int b = blockIdx.x, t = threadIdx.x;
    int flag = wb[b * Npx + t] > 0.f ? 1 : 0;
    sc[t] = flag;
    __syncthreads();
    for (int off = 1; off < 1024; off <<= 1) {
        int v = (t >= off) ? sc[t - off] : 0;
        __syncthreads();
        sc[t] += v;
        __syncthreads();
    }
    if (flag) {
        int pos = sc[t] - 1;
        jidx[b * Npx + pos] = t;
        ivg[b * Npx + pos] = invn[b * Npx + t];
    }
    if (t == 1023) nsel[b] = sc[1023];
}

// ---------------- 4d: gather selected rows of Ft -> Ftg[jc][c] ----------------
// grid (16, Bsz), block 256
__global__ void k_gather(const unsigned short* __restrict__ Ft, const int* __restrict__ nsel,
                         const int* __restrict__ jidx, unsigned short* __restrict__ Ftg) {
    int b = blockIdx.y;
    int ns = nsel[b];
    const uint4* src = (const uint4*)(Ft + (size_t)b * Npx * Cch);
    uint4* dst = (uint4*)(Ftg + (size_t)b * Npx * Cch);
    const int* ji = jidx + b * Npx;
    int total = ns * (Cch / 8);   // uint4 chunks (8 halves each)
    for (int idx = blockIdx.x * 256 + threadIdx.x; idx < total; idx += 16 * 256) {
        int jc = idx >> 6, o = idx & 63;
        dst[jc * 64 + o] = src[(size_t)ji[jc] * 64 + o];
    }
}

// ---------------- 4e: transpose Ftg -> Fg[c][jc] (stride Npx) ----------------
// grid (32, 16, Bsz), block 256
__global__ void k_trn(const unsigned short* __restrict__ Ftg, const int* __restrict__ nsel,
                      unsigned short* __restrict__ Fg) {
    int b = blockIdx.z;
    int KC = (nsel[b] + 31) & ~31;
    int j0 = blockIdx.x * 32;
    if (j0 >= KC) return;
    int c0 = blockIdx.y * 32;
    __shared__ unsigned short tt[32][33];
    int col = threadIdx.x & 31, rr = threadIdx.x >> 5;
    const unsigned short* S = Ftg + (size_t)b * Npx * Cch;
    unsigned short* D = Fg + (size_t)b * Cch * Npx;
    for (int r = rr; r < 32; r += 8) tt[r][col] = S[(size_t)(j0 + r) * Cch + c0 + col];
    __syncthreads();
    for (int r = rr; r < 32; r += 8) D[(size_t)(c0 + r) * Npx + j0 + col] = tt[col][r];
}

// ---------------- 5: Gram over compacted columns: G[i,jc] ----------------
// grid (8, 8, Bsz); j-tiles beyond KC exit
__global__ void __launch_bounds__(256) k_gram_c(const unsigned short* __restrict__ Ft,
                                                const unsigned short* __restrict__ Ftg,
                                                const int* __restrict__ nsel,
                                                unsigned short* __restrict__ G) {
    int b = blockIdx.z;
    int KC = (nsel[b] + 31) & ~31;
    int j0 = blockIdx.y * 128;
    if (j0 >= KC) return;
    int i0 = blockIdx.x * 128;
    __shared__ unsigned short At[128][40];
    __shared__ unsigned short Bt[128][40];
    const unsigned short* FA = Ft + (size_t)b * Npx * Cch;
    const unsigned short* FB = Ftg + (size_t)b * Npx * Cch;
    int tid = threadIdx.x;
    int l = tid & 63, w = tid >> 6;
    int ml = l & 15, quad = l >> 4;
    int wi = (w & 1) * 64, wj = (w >> 1) * 64;
    f32x4 acc[4][4] = {};
    for (int k0 = 0; k0 < Cch; k0 += 32) {
        #pragma unroll
        for (int s = 0; s < 2; s++) {
            int idx = tid + s * 256;
            int r = idx >> 2, kc = idx & 3;
            *(uint4*)&At[r][kc * 8] = *(const uint4*)(FA + (size_t)(i0 + r) * Cch + k0 + kc * 8);
            *(uint4*)&Bt[r][kc * 8] = *(const uint4*)(FB + (size_t)(j0 + r) * Cch + k0 + kc * 8);
        }
        __syncthreads();
        bf16x8 af[4], bfr[4];
        #pragma unroll
        for (int u = 0; u < 4; u++) af[u] = *(const bf16x8*)&At[wi + u * 16 + ml][quad * 8];
        #pragma unroll
        for (int v = 0; v < 4; v++) bfr[v] = *(const bf16x8*)&Bt[wj + v * 16 + ml][quad * 8];
        #pragma unroll
        for (int u = 0; u < 4; u++)
            #pragma unroll
            for (int v = 0; v < 4; v++)
                acc[u][v] = __builtin_amdgcn_mfma_f32_16x16x32_bf16(af[u], bfr[v], acc[u][v], 0, 0, 0);
        __syncthreads();
    }
    unsigned short* g = G + (size_t)b * Npx * Npx;
    #pragma unroll
    for (int u = 0; u < 4; u++) {
        int i = i0 + wi + u * 16 + quad * 4;
        #pragma unroll
        for (int v = 0; v < 4; v++) {
            int j = j0 + wj + v * 16 + ml;
            #pragma unroll
            for (int r = 0; r < 4; r++)
                g[(size_t)(i + r) * Npx + j] = f2bf(acc[u][v][r]);
        }
    }
}

// ---------------- 6: compact softmax, bf16 in place, zero-pads [ns,KC) -------
// grid (Npx, Bsz), block 256
__global__ void k_softmax_c(unsigned short* __restrict__ G, const float* __restrict__ invn,
                            const float* __restrict__ ivg, const int* __restrict__ nsel) {
    __shared__ float s4[4];
    int i = blockIdx.x, b = blockIdx.y, t = threadIdx.x;
    int ns = nsel[b];
    int KC = (ns + 31) & ~31;
    unsigned short* row = G + ((size_t)b * Npx + i) * Npx;
    const float* iv = ivg + (size_t)b * Npx;
    float ivi = invn[b * Npx + i];
    float vals[4];
    float mx = -INFINITY;
    #pragma unroll
    for (int q = 0; q < 4; q++) {
        int jc = q * 256 + t;
        float sv = -INFINITY;
        if (jc < ns) sv = 2.f * bf2f(row[jc]) * ivi * iv[jc];
        vals[q] = sv;
        mx = fmaxf(mx, sv);
    }
    mx = block_max256(mx, s4);   // syncthreads inside: reads done before writes
    float sum = 0.f;
    #pragma unroll
    for (int q = 0; q < 4; q++) { float e = expf(vals[q] - mx); vals[q] = e; sum += e; }
    sum = block_sum256(sum, s4);
    float inv = 1.f / sum;
    #pragma unroll
    for (int q = 0; q < 4; q++) {
        int jc = q * 256 + t;
        if (jc < KC) row[jc] = f2bf(vals[q] * inv);   // [ns,KC) gets exp(-inf)=0
    }
}

// ---------------- 7: PV over compacted K: local[c,i] = sum_jc P[i,jc] Fg[c,jc]
// grid (8, 8, Bsz), block 256
__global__ void __launch_bounds__(256) k_pv_c(const unsigned short* __restrict__ Fg,
                                              const unsigned short* __restrict__ A,
                                              const int* __restrict__ nsel,
                                              float* __restrict__ Dout) {
    int b = blockIdx.z;
    int KC = (nsel[b] + 31) & ~31;
    __shared__ unsigned short At[64][40];
    __shared__ unsigned short Bt[128][40];
    int i0 = blockIdx.x * 128, c0 = blockIdx.y * 64;
    const unsigned short* F = Fg + (size_t)b * Cch * Npx;
    const unsigned short* Ar = A + (size_t)b * Npx * Npx;
    int tid = threadIdx.x;
    int l = tid & 63, w = tid >> 6;
    int ml = l & 15, quad = l >> 4;
    int wm = (w & 1) * 32, wn = (w >> 1) * 64;
    f32x4 acc[2][4] = {};
    for (int j0 = 0; j0 < KC; j0 += 32) {
        {
            int r = tid >> 2, kc = tid & 3;
            *(uint4*)&At[r][kc * 8] = *(const uint4*)(F + (size_t)(c0 + r) * Npx + j0 + kc * 8);
        }
        #pragma unroll
        for (int s = 0; s < 2; s++) {
            int idx = tid + s * 256;
            int r = idx >> 2, kc = idx & 3;
            *(uint4*)&Bt[r][kc * 8] = *(const uint4*)(Ar + (size_t)(i0 + r) * Npx + j0 + kc * 8);
        }
        __syncthreads();
        bf16x8 af[2], bfr[4];
        #pragma unroll
        for (int u = 0; u < 2; u++) af[u] = *(const bf16x8*)&At[wm + u * 16 + ml][quad * 8];
        #pragma unroll
        for (int v = 0; v < 4; v++) bfr[v] = *(const bf16x8*)&Bt[wn + v * 16 + ml][quad * 8];
        #pragma unroll
        for (int u = 0; u < 2; u++)
            #pragma unroll
            for (int v = 0; v < 4; v++)
                acc[u][v] = __builtin_amdgcn_mfma_f32_16x16x32_bf16(af[u], bfr[v], acc[u][v], 0, 0, 0);
        __syncthreads();
    }
    float* D = Dout + (size_t)b * Cch * Npx;
    #pragma unroll
    for (int u = 0; u < 2; u++) {
        int c = c0 + wm + u * 16 + quad * 4;
        #pragma unroll
        for (int v = 0; v < 4; v++) {
            int i = i0 + wn + v * 16 + ml;
            #pragma unroll
            for (int r = 0; r < 4; r++)
                D[(size_t)(c + r) * Npx + i] = acc[u][v][r];
        }
    }
}

// ---------------- 8: final dual similarity ----------------
__global__ void k_out(const float* __restrict__ fq, const float* __restrict__ FP,
                      const float* __restrict__ fgp, const float* __restrict__ bgp,
                      const float* __restrict__ local, float* __restrict__ out) {
    __shared__ float sFP1[Cch], sBG[Cch], s4[4];
    __shared__ float rdf[8][32], rdb[8][32], rqq[8][32], rnb[8][32];
    int b = blockIdx.y, t = threadIdx.x;
    int tx = t & 31, ty = t >> 5;
    int p = blockIdx.x * 32 + tx;
    for (int c = t; c < Cch; c += 256) {
        sFP1[c] = 0.5f * FP[b * Cch + c] + 0.5f * fgp[b * Cch + c];
        sBG[c] = 0.3f * bgp[b * Cch + c];
    }
    __syncthreads();
    float nf = 0.f;
    for (int c = t; c < Cch; c += 256) nf += sFP1[c] * sFP1[c];
    nf = sqrtf(block_sum256(nf, s4));
    const float* q = fq + (size_t)b * Cch * Npx + p;
    const float* lo = local + (size_t)b * Cch * Npx + p;
    float df = 0.f, db = 0.f, qq = 0.f, nb2 = 0.f;
    int c0 = ty * 64;
    #pragma unroll 4
    for (int c = 0; c < 64; c++) {
        float v = q[(size_t)(c0 + c) * Npx];
        float bp1 = sBG[c0 + c] + 0.7f * lo[(size_t)(c0 + c) * Npx];
        df += v * sFP1[c0 + c];
        db += v * bp1;
        qq += v * v;
        nb2 += bp1 * bp1;
    }
    rdf[ty][tx] = df; rdb[ty][tx] = db; rqq[ty][tx] = qq; rnb[ty][tx] = nb2;
    __syncthreads();
    for (int s = 4; s > 0; s >>= 1) {
        if (ty < s) {
            rdf[ty][tx] += rdf[ty + s][tx];
            rdb[ty][tx] += rdb[ty + s][tx];
            rqq[ty][tx] += rqq[ty + s][tx];
            rnb[ty][tx] += rnb[ty + s][tx];
        }
        __syncthreads();
    }
    if (ty == 0) {
        float nq = sqrtf(rqq[0][tx]);
        float sf = 10.f * rdf[0][tx] / fmaxf(nq * nf, 1e-8f);
        float sb = 10.f * rdb[0][tx] / fmaxf(nq * sqrtf(rnb[0][tx]), 1e-8f);
        out[((size_t)b * 2) * Npx + p] = sb;
        out[((size_t)b * 2 + 1) * Npx + p] = sf;
    }
}

extern "C" void kernel_launch(void* const* d_in, const int* in_sizes, int n_in,
                              void* d_out, int out_size, void* d_ws, size_t ws_size,
                              hipStream_t stream) {
    const float* fq = (const float*)d_in[0];
    const float* sf = (const float*)d_in[1];
    const int* mask = (const int*)d_in[2];
    float* out = (float*)d_out;

    float* ws = (float*)d_ws;
    float* FP    = ws;                        // B*C
    float* BP    = FP + Bsz * Cch;
    float* fgp   = BP + Bsz * Cch;
    float* bgp   = fgp + Bsz * Cch;
    float* predf = bgp + Bsz * Cch;           // B*N
    float* predb = predf + Bsz * Npx;
    float* invn  = predb + Bsz * Npx;
    float* wf    = invn + Bsz * Npx;
    float* wb    = wf + Bsz * Npx;
    float* ivg   = wb + Bsz * Npx;            // B*N gathered inv-norms
    float* cnts  = ivg + Bsz * Npx;           // 16
    int*   nsel  = (int*)(cnts + 16);         // B
    int*   jidx  = nsel + 8;                  // B*N
    unsigned short* Ft  = (unsigned short*)(jidx + Bsz * Npx);        // 8 MB
    unsigned short* Ftg = Ft + (size_t)Bsz * Npx * Cch;               // 8 MB
    unsigned short* Fg  = Ftg + (size_t)Bsz * Npx * Cch;              // 8 MB
    unsigned short* Gb  = Fg + (size_t)Bsz * Cch * Npx;               // 16 MB
    float* local = (float*)(Gb + (size_t)Bsz * Npx * Npx);            // 16 MB

    k_pool<<<dim3(Cch, Bsz), 256, 0, stream>>>(sf, mask, FP, BP);
    k_pred<<<dim3(Npx / 32, Bsz), 256, 0, stream>>>(fq, FP, BP, predf, predb, invn);
    k_select<<<Bsz, 1024, 0, stream>>>(predf, 0.7f, wf, cnts);
    k_select<<<Bsz, 1024, 0, stream>>>(predb, 0.6f, wb, cnts + Bsz);
    k_proto2<<<dim3(Cch, Bsz), 256, 0, stream>>>(fq, wf, wb, cnts, fgp, bgp);
    k_cast<<<dim3(Npx / 32, Cch / 32, Bsz), 256, 0, stream>>>(fq, Ft);
    k_compact<<<Bsz, 1024, 0, stream>>>(wb, invn, nsel, jidx, ivg);
    k_gather<<<dim3(16, Bsz), 256, 0, stream>>>(Ft, nsel, jidx, Ftg);
    k_trn<<<dim3(32, 16, Bsz), 256, 0, stream>>>(Ftg, nsel, Fg);
    k_gram_c<<<dim3(8, 8, Bsz), 256, 0, stream>>>(Ft, Ftg, nsel, Gb);
    k_softmax_c<<<dim3(Npx, Bsz), 256, 0, stream>>>(Gb, invn, ivg, nsel);
    k_pv_c<<<dim3(8, 8, Bsz), 256, 0, stream>>>(Fg, Gb, nsel, local);
    k_out<<<dim3(Npx / 32, Bsz), 256, 0, stream>>>(fq, FP, fgp, bgp, local, out);
}

// Round 5
// 166.162 us; speedup vs baseline: 1.0648x; 1.0648x over previous
//
#include <hip/hip_runtime.h>
#include <math.h>

#define Bsz 8
#define Cch 512
#define Npx 1024
#define TOPK 12

typedef __attribute__((ext_vector_type(8))) short bf16x8;
typedef __attribute__((ext_vector_type(4))) float f32x4;

__device__ __forceinline__ unsigned short f2bf(float x) {
    unsigned u = __float_as_uint(x);
    u += 0x7FFF + ((u >> 16) & 1);
    return (unsigned short)(u >> 16);
}
__device__ __forceinline__ float bf2f(unsigned short h) {
    return __uint_as_float(((unsigned)h) << 16);
}

// ---------------- reduction helpers (blockDim.x == 256) ----------------
__device__ __forceinline__ float warp_sum64(float v) {
    for (int o = 32; o > 0; o >>= 1) v += __shfl_down(v, o);
    return v;
}
__device__ __forceinline__ float block_sum256(float v, float* s4) {
    v = warp_sum64(v);
    int lane = threadIdx.x & 63, w = threadIdx.x >> 6;
    __syncthreads();
    if (lane == 0) s4[w] = v;
    __syncthreads();
    return s4[0] + s4[1] + s4[2] + s4[3];
}

// ---------------- 1: masked average pool ----------------
__global__ void k_pool(const float* __restrict__ sf, const int* __restrict__ mask,
                       float* __restrict__ FPo, float* __restrict__ BPo) {
    __shared__ float s4[4];
    int c = blockIdx.x, b = blockIdx.y, t = threadIdx.x;
    const float* f = sf + ((size_t)b * Cch + c) * Npx;
    const int* m = mask + (size_t)b * Npx;
    float sumf = 0.f, sumb = 0.f, cf = 0.f, cb = 0.f;
    for (int p = t; p < Npx; p += 256) {
        float v = f[p];
        if (m[p] == 1) { sumf += v; cf += 1.f; }
        else           { sumb += v; cb += 1.f; }
    }
    sumf = block_sum256(sumf, s4);
    cf   = block_sum256(cf, s4);
    sumb = block_sum256(sumb, s4);
    cb   = block_sum256(cb, s4);
    if (t == 0) {
        FPo[b * Cch + c] = sumf / (cf + 1e-5f);
        BPo[b * Cch + c] = sumb / (cb + 1e-5f);
    }
}

// ---------------- 2: pred softmax + bf16 cast of fq tile (fused) ----------------
// grid (Npx/32, Bsz), block 256: 32 pixels/block, 8 threads/pixel (64 ch each)
__global__ void __launch_bounds__(256) k_predcast(const float* __restrict__ fq,
                       const float* __restrict__ FP, const float* __restrict__ BP,
                       float* __restrict__ predf, float* __restrict__ predb,
                       float* __restrict__ invn, unsigned short* __restrict__ Ft) {
    __shared__ float sFP[Cch], sBP[Cch], s4[4];
    __shared__ float rdf[8][32], rdb[8][32], rqq[8][32];
    __shared__ unsigned short S[32][522];   // stride 522: odd dword stride -> conflict-free
    int b = blockIdx.y, t = threadIdx.x;
    int tx = t & 31, ty = t >> 5;
    int p0 = blockIdx.x * 32;
    int p = p0 + tx;
    for (int c = t; c < Cch; c += 256) { sFP[c] = FP[b * Cch + c]; sBP[c] = BP[b * Cch + c]; }
    __syncthreads();
    float nf = 0.f, nb = 0.f;
    for (int c = t; c < Cch; c += 256) { nf += sFP[c] * sFP[c]; nb += sBP[c] * sBP[c]; }
    nf = sqrtf(block_sum256(nf, s4));
    nb = sqrtf(block_sum256(nb, s4));
    const float* q = fq + (size_t)b * Cch * Npx + p;
    float df = 0.f, db = 0.f, qq = 0.f;
    int c0 = ty * 64;
    #pragma unroll 4
    for (int c = 0; c < 64; c += 2) {
        float v0 = q[(size_t)(c0 + c) * Npx];
        float v1 = q[(size_t)(c0 + c + 1) * Npx];
        df += v0 * sFP[c0 + c] + v1 * sFP[c0 + c + 1];
        db += v0 * sBP[c0 + c] + v1 * sBP[c0 + c + 1];
        qq += v0 * v0 + v1 * v1;
        unsigned pk = (unsigned)f2bf(v0) | ((unsigned)f2bf(v1) << 16);
        *(unsigned*)&S[tx][c0 + c] = pk;
    }
    rdf[ty][tx] = df; rdb[ty][tx] = db; rqq[ty][tx] = qq;
    __syncthreads();
    for (int s = 4; s > 0; s >>= 1) {
        if (ty < s) {
            rdf[ty][tx] += rdf[ty + s][tx];
            rdb[ty][tx] += rdb[ty + s][tx];
            rqq[ty][tx] += rqq[ty + s][tx];
        }
        __syncthreads();
    }
    if (ty == 0) {
        float nq = sqrtf(rqq[0][tx]);
        float simf = 10.f * rdf[0][tx] / fmaxf(nq * nf, 1e-8f);
        float simb = 10.f * rdb[0][tx] / fmaxf(nq * nb, 1e-8f);
        predf[b * Npx + p] = 1.f / (1.f + expf(simb - simf));
        predb[b * Npx + p] = 1.f / (1.f + expf(simf - simb));
        invn[b * Npx + p] = 1.f / nq;
    }
    // write Ft rows (coalesced dword stores, conflict-free LDS dword reads)
    int w = t >> 6, lane = t & 63;
    unsigned short* FtB = Ft + (size_t)b * Npx * Cch;
    for (int pr = w; pr < 32; pr += 4) {
        unsigned* dst = (unsigned*)(FtB + (size_t)(p0 + pr) * Cch);
        #pragma unroll
        for (int it = 0; it < 4; it++) {
            int d = it * 64 + lane;            // dword index 0..255
            dst[d] = *(const unsigned*)&S[pr][d * 2];
        }
    }
}

// ---------------- 3: select + compact (fg and bg), one kernel ----------------
// grid (2, Bsz), block 1024. x=0: fg(0.7), x=1: bg(0.6)
__global__ void __launch_bounds__(1024) k_selcompact(const float* __restrict__ predf,
                        const float* __restrict__ predb, const float* __restrict__ invn,
                        int* __restrict__ nsf, int* __restrict__ nsb,
                        int* __restrict__ jf, int* __restrict__ jb,
                        float* __restrict__ ivg) {
    __shared__ int sc[Npx];
    __shared__ float v[Npx];
    __shared__ float rv[Npx];
    __shared__ int ri[Npx];
    __shared__ int cnts;
    int b = blockIdx.y, t = threadIdx.x;
    bool isf = (blockIdx.x == 0);
    const float* pr = (isf ? predf : predb) + b * Npx;
    float thres = isf ? 0.7f : 0.6f;
    float p = pr[t];
    int flag = (p > thres) ? 1 : 0;
    if (t == 0) cnts = 0;
    __syncthreads();
    atomicAdd(&cnts, flag);
    __syncthreads();
    if (cnts == 0) {
        // top-12 fallback (lower index wins ties)
        v[t] = p; flag = 0;
        __syncthreads();
        for (int k = 0; k < TOPK; k++) {
            rv[t] = v[t]; ri[t] = t;
            __syncthreads();
            for (int s = 512; s > 0; s >>= 1) {
                if (t < s) {
                    float a = rv[t], bb = rv[t + s];
                    int ia = ri[t], ib = ri[t + s];
                    if (bb > a || (bb == a && ib < ia)) { rv[t] = bb; ri[t] = ib; }
                }
                __syncthreads();
            }
            int win = ri[0];
            if (t == win) { flag = 1; v[t] = -INFINITY; }
            __syncthreads();
        }
    }
    // inclusive scan of flags (order-preserving compaction)
    sc[t] = flag;
    __syncthreads();
    for (int off = 1; off < 1024; off <<= 1) {
        int x = (t >= off) ? sc[t - off] : 0;
        __syncthreads();
        sc[t] += x;
        __syncthreads();
    }
    if (flag) {
        int pos = sc[t] - 1;
        if (isf) jf[b * Npx + pos] = t;
        else {
            jb[b * Npx + pos] = t;
            ivg[b * Npx + pos] = invn[b * Npx + t];
        }
    }
    if (t == 1023) {
        if (isf) nsf[b] = sc[1023];
        else     nsb[b] = sc[1023];
    }
}

// ---------------- 4: prototypes via index gather ----------------
// grid (Cch/32, Bsz), block 256: tx = k-parallel (32), ty = channel (8)
__global__ void k_proto_g(const float* __restrict__ fq,
                          const int* __restrict__ jf, const int* __restrict__ nsf,
                          const int* __restrict__ jb, const int* __restrict__ nsb,
                          float* __restrict__ fgp, float* __restrict__ bgp) {
    int b = blockIdx.y, cb = blockIdx.x * 32;
    int tx = threadIdx.x & 31, ty = threadIdx.x >> 5;
    const float* F = fq + (size_t)b * Cch * Npx;
    for (int which = 0; which < 2; which++) {
        const int* ji = (which ? jb : jf) + b * Npx;
        int ns = (which ? nsb : nsf)[b];
        for (int g = 0; g < 4; g++) {
            int c = cb + g * 8 + ty;
            float s = 0.f;
            for (int k = tx; k < ns; k += 32) s += F[(size_t)c * Npx + ji[k]];
            #pragma unroll
            for (int o = 16; o > 0; o >>= 1) s += __shfl_down(s, o);
            if (tx == 0) (which ? bgp : fgp)[b * Cch + c] = s / (float)ns;
        }
    }
}

// ---------------- 5: gather+transpose selected rows -> Fg[c][jc] ----------------
// grid (32, Cch/32, Bsz), block 256
__global__ void k_gtrn(const unsigned short* __restrict__ Ft, const int* __restrict__ jb,
                       const int* __restrict__ nsb, unsigned short* __restrict__ Fg) {
    int b = blockIdx.z;
    int ns = nsb[b];
    int KC = (ns + 31) & ~31;
    int j0 = blockIdx.x * 32;
    if (j0 >= KC) return;
    int c0 = blockIdx.y * 32;
    __shared__ unsigned short tt[32][33];
    int col = threadIdx.x & 31, rr = threadIdx.x >> 5;
    const unsigned short* S = Ft + (size_t)b * Npx * Cch;
    const int* ji = jb + b * Npx;
    for (int r = rr; r < 32; r += 8) {
        int j = j0 + r;
        int src = (j < ns) ? ji[j] : ji[ns - 1];   // pad rows: value irrelevant (P==0 there)
        tt[r][col] = S[(size_t)src * Cch + c0 + col];
    }
    __syncthreads();
    unsigned short* D = Fg + (size_t)b * Cch * Npx;
    for (int r = rr; r < 32; r += 8)
        D[(size_t)(c0 + r) * Npx + j0 + col] = tt[col][r];
}

// ---------------- 6: Gram over compacted columns (inline index gather) --------
// grid (8, 8, Bsz), block 256; j-tiles beyond KC exit
__global__ void __launch_bounds__(256) k_gram_c(const unsigned short* __restrict__ Ft,
                                                const int* __restrict__ jb,
                                                const int* __restrict__ nsb,
                                                unsigned short* __restrict__ G) {
    int b = blockIdx.z;
    int ns = nsb[b];
    int KC = (ns + 31) & ~31;
    int j0 = blockIdx.y * 128;
    if (j0 >= KC) return;
    int i0 = blockIdx.x * 128;
    __shared__ unsigned short At[128][40];
    __shared__ unsigned short Bt[128][40];
    __shared__ int sji[128];
    const unsigned short* FA = Ft + (size_t)b * Npx * Cch;
    int tid = threadIdx.x;
    if (tid < 128) {
        int j = j0 + tid;
        sji[tid] = (j < ns) ? jb[b * Npx + j] : jb[b * Npx];
    }
    __syncthreads();
    int l = tid & 63, w = tid >> 6;
    int ml = l & 15, quad = l >> 4;
    int wi = (w & 1) * 64, wj = (w >> 1) * 64;
    f32x4 acc[4][4] = {};
    for (int k0 = 0; k0 < Cch; k0 += 32) {
        #pragma unroll
        for (int s = 0; s < 2; s++) {
            int idx = tid + s * 256;
            int r = idx >> 2, kc = idx & 3;
            *(uint4*)&At[r][kc * 8] = *(const uint4*)(FA + (size_t)(i0 + r) * Cch + k0 + kc * 8);
            *(uint4*)&Bt[r][kc * 8] = *(const uint4*)(FA + (size_t)sji[r] * Cch + k0 + kc * 8);
        }
        __syncthreads();
        bf16x8 af[4], bfr[4];
        #pragma unroll
        for (int u = 0; u < 4; u++) af[u] = *(const bf16x8*)&At[wi + u * 16 + ml][quad * 8];
        #pragma unroll
        for (int v = 0; v < 4; v++) bfr[v] = *(const bf16x8*)&Bt[wj + v * 16 + ml][quad * 8];
        #pragma unroll
        for (int u = 0; u < 4; u++)
            #pragma unroll
            for (int v = 0; v < 4; v++)
                acc[u][v] = __builtin_amdgcn_mfma_f32_16x16x32_bf16(af[u], bfr[v], acc[u][v], 0, 0, 0);
        __syncthreads();
    }
    unsigned short* g = G + (size_t)b * Npx * Npx;
    #pragma unroll
    for (int u = 0; u < 4; u++) {
        int i = i0 + wi + u * 16 + quad * 4;
        #pragma unroll
        for (int v = 0; v < 4; v++) {
            int j = j0 + wj + v * 16 + ml;
            #pragma unroll
            for (int r = 0; r < 4; r++)
                g[(size_t)(i + r) * Npx + j] = f2bf(acc[u][v][r]);
        }
    }
}

// ---------------- 7: wave-per-row compact softmax, bf16 in place ----------------
// grid (Npx/4, Bsz), block 256 (4 waves, one row each)
__global__ void k_softmax_w(unsigned short* __restrict__ G, const float* __restrict__ invn,
                            const float* __restrict__ ivg, const int* __restrict__ nsb) {
    int b = blockIdx.y;
    int ns = nsb[b];
    int KC = (ns + 31) & ~31;
    int w = threadIdx.x >> 6, l = threadIdx.x & 63;
    int i = blockIdx.x * 4 + w;
    unsigned short* row = G + ((size_t)b * Npx + i) * Npx;
    const float* iv = ivg + (size_t)b * Npx;
    float ivi = invn[b * Npx + i];
    float vals[16];
    float mx = -INFINITY;
    #pragma unroll
    for (int k = 0; k < 16; k++) {
        int jc = k * 64 + l;
        float sv = -INFINITY;
        if (jc < ns) sv = 2.f * bf2f(row[jc]) * ivi * iv[jc];
        vals[k] = sv;
        mx = fmaxf(mx, sv);
    }
    #pragma unroll
    for (int o = 32; o > 0; o >>= 1) mx = fmaxf(mx, __shfl_xor(mx, o));
    float sum = 0.f;
    #pragma unroll
    for (int k = 0; k < 16; k++) { float e = expf(vals[k] - mx); vals[k] = e; sum += e; }
    #pragma unroll
    for (int o = 32; o > 0; o >>= 1) sum += __shfl_xor(sum, o);
    float inv = 1.f / sum;
    #pragma unroll
    for (int k = 0; k < 16; k++) {
        int jc = k * 64 + l;
        if (jc < KC) row[jc] = f2bf(vals[k] * inv);   // [ns,KC) -> 0
    }
}

// ---------------- 8: PV over compacted K -> localh (bf16) ----------------
// grid (8, 8, Bsz), block 256
__global__ void __launch_bounds__(256) k_pv_c(const unsigned short* __restrict__ Fg,
                                              const unsigned short* __restrict__ A,
                                              const int* __restrict__ nsb,
                                              unsigned short* __restrict__ Dout) {
    int b = blockIdx.z;
    int KC = (nsb[b] + 31) & ~31;
    __shared__ unsigned short At[64][40];
    __shared__ unsigned short Bt[128][40];
    int i0 = blockIdx.x * 128, c0 = blockIdx.y * 64;
    const unsigned short* F = Fg + (size_t)b * Cch * Npx;
    const unsigned short* Ar = A + (size_t)b * Npx * Npx;
    int tid = threadIdx.x;
    int l = tid & 63, w = tid >> 6;
    int ml = l & 15, quad = l >> 4;
    int wm = (w & 1) * 32, wn = (w >> 1) * 64;
    f32x4 acc[2][4] = {};
    for (int j0 = 0; j0 < KC; j0 += 32) {
        {
            int r = tid >> 2, kc = tid & 3;
            *(uint4*)&At[r][kc * 8] = *(const uint4*)(F + (size_t)(c0 + r) * Npx + j0 + kc * 8);
        }
        #pragma unroll
        for (int s = 0; s < 2; s++) {
            int idx = tid + s * 256;
            int r = idx >> 2, kc = idx & 3;
            *(uint4*)&Bt[r][kc * 8] = *(const uint4*)(Ar + (size_t)(i0 + r) * Npx + j0 + kc * 8);
        }
        __syncthreads();
        bf16x8 af[2], bfr[4];
        #pragma unroll
        for (int u = 0; u < 2; u++) af[u] = *(const bf16x8*)&At[wm + u * 16 + ml][quad * 8];
        #pragma unroll
        for (int v = 0; v < 4; v++) bfr[v] = *(const bf16x8*)&Bt[wn + v * 16 + ml][quad * 8];
        #pragma unroll
        for (int u = 0; u < 2; u++)
            #pragma unroll
            for (int v = 0; v < 4; v++)
                acc[u][v] = __builtin_amdgcn_mfma_f32_16x16x32_bf16(af[u], bfr[v], acc[u][v], 0, 0, 0);
        __syncthreads();
    }
    unsigned short* D = Dout + (size_t)b * Cch * Npx;
    #pragma unroll
    for (int u = 0; u < 2; u++) {
        int c = c0 + wm + u * 16 + quad * 4;
        #pragma unroll
        for (int v = 0; v < 4; v++) {
            int i = i0 + wn + v * 16 + ml;
            #pragma unroll
            for (int r = 0; r < 4; r++)
                D[(size_t)(c + r) * Npx + i] = f2bf(acc[u][v][r]);
        }
    }
}

// ---------------- 9: final dual similarity (local is bf16) ----------------
// grid (Npx/32, Bsz), block 256
__global__ void k_out(const float* __restrict__ fq, const float* __restrict__ FP,
                      const float* __restrict__ fgp, const float* __restrict__ bgp,
                      const unsigned short* __restrict__ localh, float* __restrict__ out) {
    __shared__ float sFP1[Cch], sBG[Cch], s4[4];
    __shared__ float rdf[8][32], rdb[8][32], rqq[8][32], rnb[8][32];
    int b = blockIdx.y, t = threadIdx.x;
    int tx = t & 31, ty = t >> 5;
    int p = blockIdx.x * 32 + tx;
    for (int c = t; c < Cch; c += 256) {
        sFP1[c] = 0.5f * FP[b * Cch + c] + 0.5f * fgp[b * Cch + c];
        sBG[c] = 0.3f * bgp[b * Cch + c];
    }
    __syncthreads();
    float nf = 0.f;
    for (int c = t; c < Cch; c += 256) nf += sFP1[c] * sFP1[c];
    nf = sqrtf(block_sum256(nf, s4));
    const float* q = fq + (size_t)b * Cch * Npx + p;
    const unsigned short* lo = localh + (size_t)b * Cch * Npx + p;
    float df = 0.f, db = 0.f, qq = 0.f, nb2 = 0.f;
    int c0 = ty * 64;
    #pragma unroll 4
    for (int c = 0; c < 64; c++) {
        float v = q[(size_t)(c0 + c) * Npx];
        float bp1 = sBG[c0 + c] + 0.7f * bf2f(lo[(size_t)(c0 + c) * Npx]);
        df += v * sFP1[c0 + c];
        db += v * bp1;
        qq += v * v;
        nb2 += bp1 * bp1;
    }
    rdf[ty][tx] = df; rdb[ty][tx] = db; rqq[ty][tx] = qq; rnb[ty][tx] = nb2;
    __syncthreads();
    for (int s = 4; s > 0; s >>= 1) {
        if (ty < s) {
            rdf[ty][tx] += rdf[ty + s][tx];
            rdb[ty][tx] += rdb[ty + s][tx];
            rqq[ty][tx] += rqq[ty + s][tx];
            rnb[ty][tx] += rnb[ty + s][tx];
        }
        __syncthreads();
    }
    if (ty == 0) {
        float nq = sqrtf(rqq[0][tx]);
        float sf = 10.f * rdf[0][tx] / fmaxf(nq * nf, 1e-8f);
        float sb = 10.f * rdb[0][tx] / fmaxf(nq * sqrtf(rnb[0][tx]), 1e-8f);
        out[((size_t)b * 2) * Npx + p] = sb;
        out[((size_t)b * 2 + 1) * Npx + p] = sf;
    }
}

extern "C" void kernel_launch(void* const* d_in, const int* in_sizes, int n_in,
                              void* d_out, int out_size, void* d_ws, size_t ws_size,
                              hipStream_t stream) {
    const float* fq = (const float*)d_in[0];
    const float* sf = (const float*)d_in[1];
    const int* mask = (const int*)d_in[2];
    float* out = (float*)d_out;

    float* ws = (float*)d_ws;
    float* FP    = ws;                        // B*C
    float* BP    = FP + Bsz * Cch;
    float* fgp   = BP + Bsz * Cch;
    float* bgp   = fgp + Bsz * Cch;
    float* predf = bgp + Bsz * Cch;           // B*N
    float* predb = predf + Bsz * Npx;
    float* invn  = predb + Bsz * Npx;
    float* ivg   = invn + Bsz * Npx;          // gathered inv-norms (bg-compacted)
    int*   nsf   = (int*)(ivg + Bsz * Npx);   // 8
    int*   nsb   = nsf + 8;                   // 8
    int*   jf    = nsb + 8;                   // B*N
    int*   jb    = jf + Bsz * Npx;            // B*N
    unsigned short* Ft     = (unsigned short*)(jb + Bsz * Npx);          // 8 MB [i][c]
    unsigned short* Fg     = Ft + (size_t)Bsz * Npx * Cch;               // 8 MB [c][jc]
    unsigned short* Gb     = Fg + (size_t)Bsz * Cch * Npx;               // 16 MB
    unsigned short* localh = Gb + (size_t)Bsz * Npx * Npx;               // 8 MB bf16

    k_pool<<<dim3(Cch, Bsz), 256, 0, stream>>>(sf, mask, FP, BP);
    k_predcast<<<dim3(Npx / 32, Bsz), 256, 0, stream>>>(fq, FP, BP, predf, predb, invn, Ft);
    k_selcompact<<<dim3(2, Bsz), 1024, 0, stream>>>(predf, predb, invn, nsf, nsb, jf, jb, ivg);
    k_proto_g<<<dim3(Cch / 32, Bsz), 256, 0, stream>>>(fq, jf, nsf, jb, nsb, fgp, bgp);
    k_gtrn<<<dim3(32, Cch / 32, Bsz), 256, 0, stream>>>(Ft, jb, nsb, Fg);
    k_gram_c<<<dim3(8, 8, Bsz), 256, 0, stream>>>(Ft, jb, nsb, Gb);
    k_softmax_w<<<dim3(Npx / 4, Bsz), 256, 0, stream>>>(Gb, invn, ivg, nsb);
    k_pv_c<<<dim3(8, 8, Bsz), 256, 0, stream>>>(Fg, Gb, nsb, localh);
    k_out<<<dim3(Npx / 32, Bsz), 256, 0, stream>>>(fq, FP, fgp, bgp, localh, out);
}